// Round 9
// baseline (61.361 us; speedup 1.0000x reference)
//
#include <hip/hip_runtime.h>
#include <math.h>

#define NN 512
#define DD 128
#define TEMP_INV (1.0f / 0.07f)
#define EPSF 1e-8f

// ws float-indexed layout (~1.06 MB used):
//   uint idx 0    : ticket (never reset; modulo-NN last-block detection)
//   ll  idx 1..4  : int64 fixed-point accums {ral_s, ral_c, oal_s, oal_c} (zeroed by prep)
//   15            : vn = ||v_prog|| + eps
//   16   +512     : sv[NN]    sorted positions (ascending)
//   528  +512     : rk[NN]    (int) stable rank of element k
//   1040 +512     : proj[NN]  raw cf . v_prog
//   1552 +512     : sqn[NN]   ||cf_k||^2 (from Gram diagonal)
//   4096 +262144  : G[NN][NN] raw Gram matrix cf @ cf^T
#define WS_VN   15
#define WS_SV   16
#define WS_RK   528
#define WS_PROJ 1040
#define WS_SQN  1552
#define WS_G    4096

#define SCALE_RAL 268435456.0   // 2^28
#define SCALE_OAL 8589934592.0  // 2^33

// prep grid: 0..1023 = gram 16x16 tiles | 1024,1025 = proj | 1026 = vn+zero | 1027,1028 = ranks
__global__ __launch_bounds__(256) void prep_kernel(
    const float* __restrict__ features,
    const float* __restrict__ labels,
    const float* __restrict__ v_prog,
    float* __restrict__ ws)
{
    const int b = blockIdx.x;
    const int t = threadIdx.x;
    if (b < 1024) {
        // ---- Gram tile (tr,tc): G[16tr..+16][16tc..+16]; 132-float padded rows
        __shared__ __align__(16) float a_s[16 * 132];
        __shared__ __align__(16) float b_s[16 * 132];
        const int tr = b >> 5, tc = b & 31;
        {
            const int rl = t >> 5, q = t & 31;          // 8 rows per half
            const int ra0 = 16 * tr + rl, rb0 = 16 * tc + rl;
            const int ra1 = ra0 + 8,      rb1 = rb0 + 8;
            float4 va0 = ((const float4*)features)[((ra0 & 255) * 2 + (ra0 >> 8)) * 32 + q];
            float4 vb0 = ((const float4*)features)[((rb0 & 255) * 2 + (rb0 >> 8)) * 32 + q];
            float4 va1 = ((const float4*)features)[((ra1 & 255) * 2 + (ra1 >> 8)) * 32 + q];
            float4 vb1 = ((const float4*)features)[((rb1 & 255) * 2 + (rb1 >> 8)) * 32 + q];
            *(float4*)(a_s + (rl + 0) * 132 + 4 * q) = va0;
            *(float4*)(b_s + (rl + 0) * 132 + 4 * q) = vb0;
            *(float4*)(a_s + (rl + 8) * 132 + 4 * q) = va1;
            *(float4*)(b_s + (rl + 8) * 132 + 4 * q) = vb1;
        }
        __syncthreads();
        const int y = t >> 4, x = t & 15;
        const float4* arow = (const float4*)(a_s + y * 132);
        const float4* brow = (const float4*)(b_s + x * 132);
        float c0 = 0.f, c1 = 0.f, c2 = 0.f, c3 = 0.f;
        #pragma unroll 8
        for (int q = 0; q < 32; ++q) {
            float4 a = arow[q]; float4 v = brow[q];
            c0 += a.x * v.x; c1 += a.y * v.y; c2 += a.z * v.z; c3 += a.w * v.w;
        }
        const float c = (c0 + c1) + (c2 + c3);
        const int gr = 16 * tr + y, gc = 16 * tc + x;
        ws[WS_G + gr * NN + gc] = c;
        if (gr == gc) ws[WS_SQN + gr] = c;              // diagonal -> sqn[]
    } else if (b < 1026) {
        // ---- proj: row = (b-1024)*256 + t
        __shared__ __align__(16) float vp_s[DD];
        if (t < DD) vp_s[t] = v_prog[t];
        __syncthreads();
        const int row = (b - 1024) * 256 + t;
        const float4* src = (const float4*)features + ((row & 255) * 2 + (row >> 8)) * 32;
        const float4* v4 = (const float4*)vp_s;
        float p0 = 0.f, p1 = 0.f, p2 = 0.f, p3 = 0.f;
        #pragma unroll 8
        for (int q = 0; q < 32; ++q) {
            float4 a = src[q]; float4 v = v4[q];
            p0 += a.x*v.x; p1 += a.y*v.y; p2 += a.z*v.z; p3 += a.w*v.w;
        }
        ws[WS_PROJ + row] = (p0 + p1) + (p2 + p3);
    } else if (b == 1026) {
        // ---- vn + zero the int64 accumulators for this launch
        __shared__ float s0[4];
        float x = (t < DD) ? v_prog[t] : 0.f;
        float s = x * x;
        #pragma unroll
        for (int o = 32; o > 0; o >>= 1) s += __shfl_down(s, o);
        if ((t & 63) == 0) s0[t >> 6] = s;
        __syncthreads();
        if (t == 0) {
            ws[WS_VN] = sqrtf(s0[0] + s0[1] + s0[2] + s0[3]) + EPSF;
            long long* acc = (long long*)ws;
            acc[1] = 0; acc[2] = 0; acc[3] = 0; acc[4] = 0;   // ticket NOT touched
        }
    } else {
        // ---- ranks: k = (b-1027)*256 + t
        __shared__ __align__(16) float pos_s[NN];
        const int k = (b - 1027) * 256 + t;
        for (int m = t; m < NN; m += 256) pos_s[m] = labels[m & 255];
        __syncthreads();
        const float pk = pos_s[k];
        const float4* p4 = (const float4*)pos_s;
        int r = 0;
        #pragma unroll 8
        for (int q = 0; q < NN / 4; ++q) {
            float4 v = p4[q];
            const int m0 = 4 * q;
            r += (int)(v.x < pk) | ((int)(v.x == pk) & (int)(m0 + 0 < k));
            r += (int)(v.y < pk) | ((int)(v.y == pk) & (int)(m0 + 1 < k));
            r += (int)(v.z < pk) | ((int)(v.z == pk) & (int)(m0 + 2 < k));
            r += (int)(v.w < pk) | ((int)(v.w == pk) & (int)(m0 + 3 < k));
        }
        ws[WS_SV + r] = pk;                 // unique slot (stable tie-break)
        ((int*)ws)[WS_RK + k] = r;
    }
}

// One block (512 threads) per row i; thread t is both k=t and j=t.
// Finale folded in: int64 fixed-point atomics + modulo ticket, last block writes out.
__global__ __launch_bounds__(512) void main_kernel(
    const float* __restrict__ labels,
    float* __restrict__ ws,
    float* __restrict__ out)
{
    __shared__ float sv_s[NN];
    __shared__ float esS[NN];
    __shared__ float wtot[8];
    __shared__ float red_s[32];
    __shared__ int is_last;

    const int i = blockIdx.x;
    const int t = threadIdx.x;

    sv_s[t] = ws[WS_SV + t];
    const int rk_t = ((const int*)ws)[WS_RK + t];
    const int rk_i = ((const int*)ws)[WS_RK + i];      // uniform
    const float g      = ws[WS_G + i * NN + t];        // coalesced Gram row
    const float sqn_i  = ws[WS_SQN + i];               // uniform
    const float sqn_k  = ws[WS_SQN + t];               // coalesced
    const float proj_i = ws[WS_PROJ + i];
    const float proj_k = ws[WS_PROJ + t];
    const float vn     = ws[WS_VN];
    const float pos_i  = labels[i & 255];
    const float pos_k  = labels[t & 255];

    const float inv_ni = 1.0f / fmaxf(sqrtf(sqn_i), 1e-12f);
    const float inv_nk = 1.0f / fmaxf(sqrtf(sqn_k), 1e-12f);
    const float sim    = g * inv_ni * inv_nk * TEMP_INV;
    const float es     = (t == i) ? 0.0f : __expf(sim);   // k==i excluded
    esS[rk_t] = es;                                        // scatter to sorted slot

    float oal_sum = 0.f, oal_cnt = 0.f;
    if (pos_i < pos_k) {
        float sqd  = fmaxf(sqn_i + sqn_k - 2.0f * g, 0.0f);
        float dist = sqrtf(fmaxf(sqd, 1e-24f));
        oal_sum = (proj_k - proj_i) / (vn * fmaxf(dist, 1e-12f));
        oal_cnt = 1.0f;
    }
    __syncthreads();   // sv_s + esS complete

    // ---- inclusive prefix scan of esS[512]
    float s = esS[t];
    #pragma unroll
    for (int off = 1; off < 64; off <<= 1) {
        float u = __shfl_up(s, off);
        if ((t & 63) >= off) s += u;
    }
    const int wid = t >> 6;
    if ((t & 63) == 63) wtot[wid] = s;
    __syncthreads();
    float woff = 0.f;
    for (int w = 0; w < wid; ++w) woff += wtot[w];    // wave-uniform
    esS[t] = s + woff;
    __syncthreads();
    const float total = esS[NN - 1];

    // ---- denom: interval of {k : |p_i - p_k| < thr}; split at rk_i; lo/hi interleaved
    const float thr = fabsf(pos_i - pos_k);           // pd[i][j], j==t
    int lo = 0, hi = rk_i;
    #pragma unroll
    for (int step = 256; step > 0; step >>= 1) {
        if (lo + step <= rk_i && !(fabsf(pos_i - sv_s[lo + step - 1]) < thr)) lo += step;
        if (hi + step <= NN   &&  (fabsf(pos_i - sv_s[hi + step - 1]) < thr)) hi += step;
    }

    const float pe_lo = (lo > 0) ? esS[lo - 1] : 0.0f;
    const float pe_hi = (hi > 0) ? esS[hi - 1] : 0.0f;
    float ral_sum = 0.f, ral_cnt = 0.f;
    if (t != i) {
        float denom = fmaxf(pe_lo + (total - pe_hi), es);   // k=j always in set
        const float sw = 1.0f / (1.0f + __expf(-thr));      // sigmoid(pd)
        ral_sum = (__logf(denom + EPSF) - sim) * sw;        // -log(es/(denom+eps))
        ral_cnt = 1.0f;
    }

    // ---- block reduce
    #pragma unroll
    for (int o = 32; o > 0; o >>= 1) {
        ral_sum += __shfl_down(ral_sum, o);
        ral_cnt += __shfl_down(ral_cnt, o);
        oal_sum += __shfl_down(oal_sum, o);
        oal_cnt += __shfl_down(oal_cnt, o);
    }
    if ((t & 63) == 0) {
        red_s[wid*4+0] = ral_sum; red_s[wid*4+1] = ral_cnt;
        red_s[wid*4+2] = oal_sum; red_s[wid*4+3] = oal_cnt;
    }
    __syncthreads();
    if (t == 0) {
        float rs = 0.f, rc = 0.f, os = 0.f, oc = 0.f;
        #pragma unroll
        for (int w = 0; w < 8; ++w) {
            rs += red_s[w*4+0]; rc += red_s[w*4+1];
            os += red_s[w*4+2]; oc += red_s[w*4+3];
        }
        // int64 fixed-point adds: commutative & exact -> deterministic
        long long* acc = (long long*)ws;
        __hip_atomic_fetch_add(&acc[1], llrint((double)rs * SCALE_RAL), __ATOMIC_RELAXED, __HIP_MEMORY_SCOPE_AGENT);
        __hip_atomic_fetch_add(&acc[2], llrint((double)rc),             __ATOMIC_RELAXED, __HIP_MEMORY_SCOPE_AGENT);
        __hip_atomic_fetch_add(&acc[3], llrint((double)os * SCALE_OAL), __ATOMIC_RELAXED, __HIP_MEMORY_SCOPE_AGENT);
        __hip_atomic_fetch_add(&acc[4], llrint((double)oc),             __ATOMIC_RELAXED, __HIP_MEMORY_SCOPE_AGENT);
        // modulo ticket: release orders the adds above; works from any poison value
        unsigned old = __hip_atomic_fetch_add((unsigned*)ws, 1u, __ATOMIC_ACQ_REL,
                                              __HIP_MEMORY_SCOPE_AGENT);
        is_last = ((old & (NN - 1u)) == NN - 1u);
    }
    __syncthreads();

    if (is_last && t == 0) {
        long long* acc = (long long*)ws;
        double RS = (double)__hip_atomic_load(&acc[1], __ATOMIC_RELAXED, __HIP_MEMORY_SCOPE_AGENT) / SCALE_RAL;
        double RC = (double)__hip_atomic_load(&acc[2], __ATOMIC_RELAXED, __HIP_MEMORY_SCOPE_AGENT);
        double OS = (double)__hip_atomic_load(&acc[3], __ATOMIC_RELAXED, __HIP_MEMORY_SCOPE_AGENT) / SCALE_OAL;
        double OC = (double)__hip_atomic_load(&acc[4], __ATOMIC_RELAXED, __HIP_MEMORY_SCOPE_AGENT);
        double ral = (RC > 0.0) ? RS / RC : 0.0;
        double oal = (OC > 0.0) ? -(OS / OC) : 0.0;
        out[0] = (float)(ral + oal);
    }
}

extern "C" void kernel_launch(void* const* d_in, const int* in_sizes, int n_in,
                              void* d_out, int out_size, void* d_ws, size_t ws_size,
                              hipStream_t stream) {
    const float* features = (const float*)d_in[0];
    const float* labels   = (const float*)d_in[1];
    const float* v_prog   = (const float*)d_in[2];
    float* ws  = (float*)d_ws;
    float* out = (float*)d_out;

    hipLaunchKernelGGL(prep_kernel, dim3(1029), dim3(256), 0, stream,
                       features, labels, v_prog, ws);
    hipLaunchKernelGGL(main_kernel, dim3(NN),   dim3(512), 0, stream, labels, ws, out);
}

// Round 11
// 44.919 us; speedup vs baseline: 1.3660x; 1.3660x over previous
//
#include <hip/hip_runtime.h>
#include <math.h>

#define NN 512
#define DD 128
#define TEMP_INV (1.0f / 0.07f)
#define EPSF 1e-8f

// ws float-indexed layout (~1.06 MB used):
//   uint idx 0    : ticket (never reset; modulo-NN last-block detection)
//   15            : vn = ||v_prog|| + eps
//   16   +512     : sv[NN]    sorted positions (ascending)
//   528  +512     : rk[NN]    (int) stable rank of element k
//   1040 +512     : proj[NN]  raw cf . v_prog
//   1552 +512     : sqn[NN]   ||cf_k||^2 (from Gram diagonal)
//   2064 +2048    : partials SoA float[4][NN] {ral_s, ral_c, oal_s, oal_c}
//   4096 +262144  : G[NN][NN] raw Gram matrix cf @ cf^T
#define WS_VN   15
#define WS_SV   16
#define WS_RK   528
#define WS_PROJ 1040
#define WS_SQN  1552
#define WS_PART 2064
#define WS_G    4096

// prep grid: 0..1023 = gram 16x16 tiles | 1024,1025 = proj | 1026 = vn | 1027,1028 = ranks
__global__ __launch_bounds__(256) void prep_kernel(
    const float* __restrict__ features,
    const float* __restrict__ labels,
    const float* __restrict__ v_prog,
    float* __restrict__ ws)
{
    const int b = blockIdx.x;
    const int t = threadIdx.x;
    if (b < 1024) {
        // ---- Gram tile (tr,tc): G[16tr..+16][16tc..+16]; 132-float padded rows
        __shared__ __align__(16) float a_s[16 * 132];
        __shared__ __align__(16) float b_s[16 * 132];
        const int tr = b >> 5, tc = b & 31;
        {
            const int rl = t >> 5, q = t & 31;          // 8 rows per half
            const int ra0 = 16 * tr + rl, rb0 = 16 * tc + rl;
            const int ra1 = ra0 + 8,      rb1 = rb0 + 8;
            float4 va0 = ((const float4*)features)[((ra0 & 255) * 2 + (ra0 >> 8)) * 32 + q];
            float4 vb0 = ((const float4*)features)[((rb0 & 255) * 2 + (rb0 >> 8)) * 32 + q];
            float4 va1 = ((const float4*)features)[((ra1 & 255) * 2 + (ra1 >> 8)) * 32 + q];
            float4 vb1 = ((const float4*)features)[((rb1 & 255) * 2 + (rb1 >> 8)) * 32 + q];
            *(float4*)(a_s + (rl + 0) * 132 + 4 * q) = va0;
            *(float4*)(b_s + (rl + 0) * 132 + 4 * q) = vb0;
            *(float4*)(a_s + (rl + 8) * 132 + 4 * q) = va1;
            *(float4*)(b_s + (rl + 8) * 132 + 4 * q) = vb1;
        }
        __syncthreads();
        const int y = t >> 4, x = t & 15;
        const float4* arow = (const float4*)(a_s + y * 132);
        const float4* brow = (const float4*)(b_s + x * 132);
        float c0 = 0.f, c1 = 0.f, c2 = 0.f, c3 = 0.f;
        #pragma unroll 8
        for (int q = 0; q < 32; ++q) {
            float4 a = arow[q]; float4 v = brow[q];
            c0 += a.x * v.x; c1 += a.y * v.y; c2 += a.z * v.z; c3 += a.w * v.w;
        }
        const float c = (c0 + c1) + (c2 + c3);
        const int gr = 16 * tr + y, gc = 16 * tc + x;
        ws[WS_G + gr * NN + gc] = c;
        if (gr == gc) ws[WS_SQN + gr] = c;              // diagonal -> sqn[]
    } else if (b < 1026) {
        // ---- proj: row = (b-1024)*256 + t
        __shared__ __align__(16) float vp_s[DD];
        if (t < DD) vp_s[t] = v_prog[t];
        __syncthreads();
        const int row = (b - 1024) * 256 + t;
        const float4* src = (const float4*)features + ((row & 255) * 2 + (row >> 8)) * 32;
        const float4* v4 = (const float4*)vp_s;
        float p0 = 0.f, p1 = 0.f, p2 = 0.f, p3 = 0.f;
        #pragma unroll 8
        for (int q = 0; q < 32; ++q) {
            float4 a = src[q]; float4 v = v4[q];
            p0 += a.x*v.x; p1 += a.y*v.y; p2 += a.z*v.z; p3 += a.w*v.w;
        }
        ws[WS_PROJ + row] = (p0 + p1) + (p2 + p3);
    } else if (b == 1026) {
        // ---- vn
        __shared__ float s0[4];
        float x = (t < DD) ? v_prog[t] : 0.f;
        float s = x * x;
        #pragma unroll
        for (int o = 32; o > 0; o >>= 1) s += __shfl_down(s, o);
        if ((t & 63) == 0) s0[t >> 6] = s;
        __syncthreads();
        if (t == 0) ws[WS_VN] = sqrtf(s0[0] + s0[1] + s0[2] + s0[3]) + EPSF;
    } else {
        // ---- ranks: k = (b-1027)*256 + t
        __shared__ __align__(16) float pos_s[NN];
        const int k = (b - 1027) * 256 + t;
        for (int m = t; m < NN; m += 256) pos_s[m] = labels[m & 255];
        __syncthreads();
        const float pk = pos_s[k];
        const float4* p4 = (const float4*)pos_s;
        int r = 0;
        #pragma unroll 8
        for (int q = 0; q < NN / 4; ++q) {
            float4 v = p4[q];
            const int m0 = 4 * q;
            r += (int)(v.x < pk) | ((int)(v.x == pk) & (int)(m0 + 0 < k));
            r += (int)(v.y < pk) | ((int)(v.y == pk) & (int)(m0 + 1 < k));
            r += (int)(v.z < pk) | ((int)(v.z == pk) & (int)(m0 + 2 < k));
            r += (int)(v.w < pk) | ((int)(v.w == pk) & (int)(m0 + 3 < k));
        }
        ws[WS_SV + r] = pk;                 // unique slot (stable tie-break)
        ((int*)ws)[WS_RK + k] = r;
    }
}

// One block (512 threads) per row i; thread t is both k=t and j=t.
// Finale folded in via SoA plain stores + threadfence + ONE ticket RMW per block.
__global__ __launch_bounds__(512) void main_kernel(
    const float* __restrict__ labels,
    float* __restrict__ ws,
    float* __restrict__ out)
{
    __shared__ float sv_s[NN];
    __shared__ float esS[NN];
    __shared__ float wtot[8];
    __shared__ float red_s[32];
    __shared__ double dred[32];
    __shared__ int is_last;

    const int i = blockIdx.x;
    const int t = threadIdx.x;
    const int wid = t >> 6;

    sv_s[t] = ws[WS_SV + t];
    const int rk_t = ((const int*)ws)[WS_RK + t];
    const int rk_i = ((const int*)ws)[WS_RK + i];      // uniform
    const float g      = ws[WS_G + i * NN + t];        // coalesced Gram row
    const float sqn_i  = ws[WS_SQN + i];               // uniform
    const float sqn_k  = ws[WS_SQN + t];               // coalesced
    const float proj_i = ws[WS_PROJ + i];
    const float proj_k = ws[WS_PROJ + t];
    const float vn     = ws[WS_VN];
    const float pos_i  = labels[i & 255];
    const float pos_k  = labels[t & 255];

    const float inv_ni = 1.0f / fmaxf(sqrtf(sqn_i), 1e-12f);
    const float inv_nk = 1.0f / fmaxf(sqrtf(sqn_k), 1e-12f);
    const float sim    = g * inv_ni * inv_nk * TEMP_INV;
    const float es     = (t == i) ? 0.0f : __expf(sim);   // k==i excluded
    esS[rk_t] = es;                                        // scatter to sorted slot

    float oal_sum = 0.f, oal_cnt = 0.f;
    if (pos_i < pos_k) {
        float sqd  = fmaxf(sqn_i + sqn_k - 2.0f * g, 0.0f);
        float dist = sqrtf(fmaxf(sqd, 1e-24f));
        oal_sum = (proj_k - proj_i) / (vn * fmaxf(dist, 1e-12f));
        oal_cnt = 1.0f;
    }
    __syncthreads();   // sv_s + esS complete

    // ---- inclusive prefix scan of esS[512]
    float s = esS[t];
    #pragma unroll
    for (int off = 1; off < 64; off <<= 1) {
        float u = __shfl_up(s, off);
        if ((t & 63) >= off) s += u;
    }
    if ((t & 63) == 63) wtot[wid] = s;
    __syncthreads();
    float woff = 0.f;
    for (int w = 0; w < wid; ++w) woff += wtot[w];    // wave-uniform
    esS[t] = s + woff;
    __syncthreads();
    const float total = esS[NN - 1];

    // ---- denom: interval of {k : |p_i - p_k| < thr}; split at rk_i; lo/hi interleaved
    const float thr = fabsf(pos_i - pos_k);           // pd[i][j], j==t
    int lo = 0, hi = rk_i;
    #pragma unroll
    for (int step = 256; step > 0; step >>= 1) {
        if (lo + step <= rk_i && !(fabsf(pos_i - sv_s[lo + step - 1]) < thr)) lo += step;
        if (hi + step <= NN   &&  (fabsf(pos_i - sv_s[hi + step - 1]) < thr)) hi += step;
    }

    const float pe_lo = (lo > 0) ? esS[lo - 1] : 0.0f;
    const float pe_hi = (hi > 0) ? esS[hi - 1] : 0.0f;
    float ral_sum = 0.f, ral_cnt = 0.f;
    if (t != i) {
        float denom = fmaxf(pe_lo + (total - pe_hi), es);   // k=j always in set
        const float sw = 1.0f / (1.0f + __expf(-thr));      // sigmoid(pd)
        ral_sum = (__logf(denom + EPSF) - sim) * sw;        // -log(es/(denom+eps))
        ral_cnt = 1.0f;
    }

    // ---- block reduce
    #pragma unroll
    for (int o = 32; o > 0; o >>= 1) {
        ral_sum += __shfl_down(ral_sum, o);
        ral_cnt += __shfl_down(ral_cnt, o);
        oal_sum += __shfl_down(oal_sum, o);
        oal_cnt += __shfl_down(oal_cnt, o);
    }
    if ((t & 63) == 0) {
        red_s[wid*4+0] = ral_sum; red_s[wid*4+1] = ral_cnt;
        red_s[wid*4+2] = oal_sum; red_s[wid*4+3] = oal_cnt;
    }
    __syncthreads();
    if (t == 0) {
        float rs = 0.f, rc = 0.f, os = 0.f, oc = 0.f;
        #pragma unroll
        for (int w = 0; w < 8; ++w) {
            rs += red_s[w*4+0]; rc += red_s[w*4+1];
            os += red_s[w*4+2]; oc += red_s[w*4+3];
        }
        // SoA plain stores, then ONE ticket RMW (release via fence + acq-rel chain)
        ws[WS_PART + 0*NN + i] = rs;
        ws[WS_PART + 1*NN + i] = rc;
        ws[WS_PART + 2*NN + i] = os;
        ws[WS_PART + 3*NN + i] = oc;
        __threadfence();
        // modulo ticket: works from any poison value; 2^32 % NN == 0
        unsigned old = __hip_atomic_fetch_add((unsigned*)ws, 1u, __ATOMIC_ACQ_REL,
                                              __HIP_MEMORY_SCOPE_AGENT);
        is_last = ((old & (NN - 1u)) == NN - 1u);
    }
    __syncthreads();

    // ---- last block: fixed-order double reduction (deterministic)
    if (is_last) {
        double rs = (double)__hip_atomic_load(ws + WS_PART + 0*NN + t, __ATOMIC_RELAXED, __HIP_MEMORY_SCOPE_AGENT);
        double rc = (double)__hip_atomic_load(ws + WS_PART + 1*NN + t, __ATOMIC_RELAXED, __HIP_MEMORY_SCOPE_AGENT);
        double os = (double)__hip_atomic_load(ws + WS_PART + 2*NN + t, __ATOMIC_RELAXED, __HIP_MEMORY_SCOPE_AGENT);
        double oc = (double)__hip_atomic_load(ws + WS_PART + 3*NN + t, __ATOMIC_RELAXED, __HIP_MEMORY_SCOPE_AGENT);
        #pragma unroll
        for (int o = 32; o > 0; o >>= 1) {
            rs += __shfl_down(rs, o);
            rc += __shfl_down(rc, o);
            os += __shfl_down(os, o);
            oc += __shfl_down(oc, o);
        }
        if ((t & 63) == 0) {
            dred[wid*4+0] = rs; dred[wid*4+1] = rc;
            dred[wid*4+2] = os; dred[wid*4+3] = oc;
        }
        __syncthreads();
        if (t == 0) {
            double RS = 0, RC = 0, OS = 0, OC = 0;
            #pragma unroll
            for (int w = 0; w < 8; ++w) {
                RS += dred[w*4+0]; RC += dred[w*4+1];
                OS += dred[w*4+2]; OC += dred[w*4+3];
            }
            double ral = (RC > 0.0) ? RS / RC : 0.0;
            double oal = (OC > 0.0) ? -(OS / OC) : 0.0;
            out[0] = (float)(ral + oal);
        }
    }
}

extern "C" void kernel_launch(void* const* d_in, const int* in_sizes, int n_in,
                              void* d_out, int out_size, void* d_ws, size_t ws_size,
                              hipStream_t stream) {
    const float* features = (const float*)d_in[0];
    const float* labels   = (const float*)d_in[1];
    const float* v_prog   = (const float*)d_in[2];
    float* ws  = (float*)d_ws;
    float* out = (float*)d_out;

    hipLaunchKernelGGL(prep_kernel, dim3(1029), dim3(256), 0, stream,
                       features, labels, v_prog, ws);
    hipLaunchKernelGGL(main_kernel, dim3(NN),   dim3(512), 0, stream, labels, ws, out);
}

// Round 12
// 34.205 us; speedup vs baseline: 1.7939x; 1.3132x over previous
//
#include <hip/hip_runtime.h>
#include <math.h>

#define NN 512
#define DD 128
#define TEMP_INV (1.0f / 0.07f)
#define EPSF 1e-8f

// ws float-indexed layout (~1.06 MB used):
//   uint idx 0    : ticket (never reset; modulo-NN last-block detection)
//   15            : vn = ||v_prog|| + eps
//   16   +512     : sv[NN]    sorted positions (ascending)
//   528  +512     : rk[NN]    (int) stable rank of element k
//   1040 +512     : proj[NN]  raw cf . v_prog
//   1552 +512     : sqn[NN]   ||cf_k||^2 (from Gram diagonal)
//   2064 +2048    : partials SoA float[4][NN] (agent-scope atomic stores)
//   4096 +262144  : G[NN][NN] raw Gram matrix cf @ cf^T
#define WS_VN   15
#define WS_SV   16
#define WS_RK   528
#define WS_PROJ 1040
#define WS_SQN  1552
#define WS_PART 2064
#define WS_G    4096

// prep grid: 0..1023 = gram 16x16 tiles | 1024,1025 = proj | 1026 = vn | 1027,1028 = ranks
__global__ __launch_bounds__(256) void prep_kernel(
    const float* __restrict__ features,
    const float* __restrict__ labels,
    const float* __restrict__ v_prog,
    float* __restrict__ ws)
{
    const int b = blockIdx.x;
    const int t = threadIdx.x;
    if (b < 1024) {
        // ---- Gram tile (tr,tc): G[16tr..+16][16tc..+16]; 132-float padded rows
        __shared__ __align__(16) float a_s[16 * 132];
        __shared__ __align__(16) float b_s[16 * 132];
        const int tr = b >> 5, tc = b & 31;
        {
            const int rl = t >> 5, q = t & 31;          // 8 rows per half
            const int ra0 = 16 * tr + rl, rb0 = 16 * tc + rl;
            const int ra1 = ra0 + 8,      rb1 = rb0 + 8;
            float4 va0 = ((const float4*)features)[((ra0 & 255) * 2 + (ra0 >> 8)) * 32 + q];
            float4 vb0 = ((const float4*)features)[((rb0 & 255) * 2 + (rb0 >> 8)) * 32 + q];
            float4 va1 = ((const float4*)features)[((ra1 & 255) * 2 + (ra1 >> 8)) * 32 + q];
            float4 vb1 = ((const float4*)features)[((rb1 & 255) * 2 + (rb1 >> 8)) * 32 + q];
            *(float4*)(a_s + (rl + 0) * 132 + 4 * q) = va0;
            *(float4*)(b_s + (rl + 0) * 132 + 4 * q) = vb0;
            *(float4*)(a_s + (rl + 8) * 132 + 4 * q) = va1;
            *(float4*)(b_s + (rl + 8) * 132 + 4 * q) = vb1;
        }
        __syncthreads();
        const int y = t >> 4, x = t & 15;
        const float4* arow = (const float4*)(a_s + y * 132);
        const float4* brow = (const float4*)(b_s + x * 132);
        float c0 = 0.f, c1 = 0.f, c2 = 0.f, c3 = 0.f;
        #pragma unroll 8
        for (int q = 0; q < 32; ++q) {
            float4 a = arow[q]; float4 v = brow[q];
            c0 += a.x * v.x; c1 += a.y * v.y; c2 += a.z * v.z; c3 += a.w * v.w;
        }
        const float c = (c0 + c1) + (c2 + c3);
        const int gr = 16 * tr + y, gc = 16 * tc + x;
        ws[WS_G + gr * NN + gc] = c;
        if (gr == gc) ws[WS_SQN + gr] = c;              // diagonal -> sqn[]
    } else if (b < 1026) {
        // ---- proj: row = (b-1024)*256 + t
        __shared__ __align__(16) float vp_s[DD];
        if (t < DD) vp_s[t] = v_prog[t];
        __syncthreads();
        const int row = (b - 1024) * 256 + t;
        const float4* src = (const float4*)features + ((row & 255) * 2 + (row >> 8)) * 32;
        const float4* v4 = (const float4*)vp_s;
        float p0 = 0.f, p1 = 0.f, p2 = 0.f, p3 = 0.f;
        #pragma unroll 8
        for (int q = 0; q < 32; ++q) {
            float4 a = src[q]; float4 v = v4[q];
            p0 += a.x*v.x; p1 += a.y*v.y; p2 += a.z*v.z; p3 += a.w*v.w;
        }
        ws[WS_PROJ + row] = (p0 + p1) + (p2 + p3);
    } else if (b == 1026) {
        // ---- vn
        __shared__ float s0[4];
        float x = (t < DD) ? v_prog[t] : 0.f;
        float s = x * x;
        #pragma unroll
        for (int o = 32; o > 0; o >>= 1) s += __shfl_down(s, o);
        if ((t & 63) == 0) s0[t >> 6] = s;
        __syncthreads();
        if (t == 0) ws[WS_VN] = sqrtf(s0[0] + s0[1] + s0[2] + s0[3]) + EPSF;
    } else {
        // ---- ranks: k = (b-1027)*256 + t
        __shared__ __align__(16) float pos_s[NN];
        const int k = (b - 1027) * 256 + t;
        for (int m = t; m < NN; m += 256) pos_s[m] = labels[m & 255];
        __syncthreads();
        const float pk = pos_s[k];
        const float4* p4 = (const float4*)pos_s;
        int r = 0;
        #pragma unroll 8
        for (int q = 0; q < NN / 4; ++q) {
            float4 v = p4[q];
            const int m0 = 4 * q;
            r += (int)(v.x < pk) | ((int)(v.x == pk) & (int)(m0 + 0 < k));
            r += (int)(v.y < pk) | ((int)(v.y == pk) & (int)(m0 + 1 < k));
            r += (int)(v.z < pk) | ((int)(v.z == pk) & (int)(m0 + 2 < k));
            r += (int)(v.w < pk) | ((int)(v.w == pk) & (int)(m0 + 3 < k));
        }
        ws[WS_SV + r] = pk;                 // unique slot (stable tie-break)
        ((int*)ws)[WS_RK + k] = r;
    }
}

// One block (512 threads) per row i; thread t is both k=t and j=t.
// Finale folded in: sc1 atomic partial stores + raw vmcnt drain + RELAXED ticket
// (no fence -> no buffer_wbl2). Last block reads partials with sc1 atomic loads.
__global__ __launch_bounds__(512) void main_kernel(
    const float* __restrict__ labels,
    float* __restrict__ ws,
    float* __restrict__ out)
{
    __shared__ float sv_s[NN];
    __shared__ float esS[NN];
    __shared__ float wtot[8];
    __shared__ float red_s[32];
    __shared__ double dred[32];
    __shared__ int is_last;

    const int i = blockIdx.x;
    const int t = threadIdx.x;
    const int wid = t >> 6;

    sv_s[t] = ws[WS_SV + t];
    const int rk_t = ((const int*)ws)[WS_RK + t];
    const int rk_i = ((const int*)ws)[WS_RK + i];      // uniform
    const float g      = ws[WS_G + i * NN + t];        // coalesced Gram row
    const float sqn_i  = ws[WS_SQN + i];               // uniform
    const float sqn_k  = ws[WS_SQN + t];               // coalesced
    const float proj_i = ws[WS_PROJ + i];
    const float proj_k = ws[WS_PROJ + t];
    const float vn     = ws[WS_VN];
    const float pos_i  = labels[i & 255];
    const float pos_k  = labels[t & 255];

    const float inv_ni = 1.0f / fmaxf(sqrtf(sqn_i), 1e-12f);
    const float inv_nk = 1.0f / fmaxf(sqrtf(sqn_k), 1e-12f);
    const float sim    = g * inv_ni * inv_nk * TEMP_INV;
    const float es     = (t == i) ? 0.0f : __expf(sim);   // k==i excluded
    esS[rk_t] = es;                                        // scatter to sorted slot

    float oal_sum = 0.f, oal_cnt = 0.f;
    if (pos_i < pos_k) {
        float sqd  = fmaxf(sqn_i + sqn_k - 2.0f * g, 0.0f);
        float dist = sqrtf(fmaxf(sqd, 1e-24f));
        oal_sum = (proj_k - proj_i) / (vn * fmaxf(dist, 1e-12f));
        oal_cnt = 1.0f;
    }
    __syncthreads();   // sv_s + esS complete

    // ---- inclusive prefix scan of esS[512]
    float s = esS[t];
    #pragma unroll
    for (int off = 1; off < 64; off <<= 1) {
        float u = __shfl_up(s, off);
        if ((t & 63) >= off) s += u;
    }
    if ((t & 63) == 63) wtot[wid] = s;
    __syncthreads();
    float woff = 0.f;
    for (int w = 0; w < wid; ++w) woff += wtot[w];    // wave-uniform
    esS[t] = s + woff;
    __syncthreads();
    const float total = esS[NN - 1];

    // ---- denom: interval of {k : |p_i - p_k| < thr}; split at rk_i; lo/hi interleaved
    const float thr = fabsf(pos_i - pos_k);           // pd[i][j], j==t
    int lo = 0, hi = rk_i;
    #pragma unroll
    for (int step = 256; step > 0; step >>= 1) {
        if (lo + step <= rk_i && !(fabsf(pos_i - sv_s[lo + step - 1]) < thr)) lo += step;
        if (hi + step <= NN   &&  (fabsf(pos_i - sv_s[hi + step - 1]) < thr)) hi += step;
    }

    const float pe_lo = (lo > 0) ? esS[lo - 1] : 0.0f;
    const float pe_hi = (hi > 0) ? esS[hi - 1] : 0.0f;
    float ral_sum = 0.f, ral_cnt = 0.f;
    if (t != i) {
        float denom = fmaxf(pe_lo + (total - pe_hi), es);   // k=j always in set
        const float sw = 1.0f / (1.0f + __expf(-thr));      // sigmoid(pd)
        ral_sum = (__logf(denom + EPSF) - sim) * sw;        // -log(es/(denom+eps))
        ral_cnt = 1.0f;
    }

    // ---- block reduce
    #pragma unroll
    for (int o = 32; o > 0; o >>= 1) {
        ral_sum += __shfl_down(ral_sum, o);
        ral_cnt += __shfl_down(ral_cnt, o);
        oal_sum += __shfl_down(oal_sum, o);
        oal_cnt += __shfl_down(oal_cnt, o);
    }
    if ((t & 63) == 0) {
        red_s[wid*4+0] = ral_sum; red_s[wid*4+1] = ral_cnt;
        red_s[wid*4+2] = oal_sum; red_s[wid*4+3] = oal_cnt;
    }
    __syncthreads();
    if (t == 0) {
        float rs = 0.f, rc = 0.f, os = 0.f, oc = 0.f;
        #pragma unroll
        for (int w = 0; w < 8; ++w) {
            rs += red_s[w*4+0]; rc += red_s[w*4+1];
            os += red_s[w*4+2]; oc += red_s[w*4+3];
        }
        // agent-scope relaxed atomic stores: write through to coherent point (sc1)
        __hip_atomic_store(ws + WS_PART + 0*NN + i, rs, __ATOMIC_RELAXED, __HIP_MEMORY_SCOPE_AGENT);
        __hip_atomic_store(ws + WS_PART + 1*NN + i, rc, __ATOMIC_RELAXED, __HIP_MEMORY_SCOPE_AGENT);
        __hip_atomic_store(ws + WS_PART + 2*NN + i, os, __ATOMIC_RELAXED, __HIP_MEMORY_SCOPE_AGENT);
        __hip_atomic_store(ws + WS_PART + 3*NN + i, oc, __ATOMIC_RELAXED, __HIP_MEMORY_SCOPE_AGENT);
        // drain the stores to the coherent point, then RELAXED ticket (no wbl2)
        asm volatile("s_waitcnt vmcnt(0)" ::: "memory");
        unsigned old = __hip_atomic_fetch_add((unsigned*)ws, 1u, __ATOMIC_RELAXED,
                                              __HIP_MEMORY_SCOPE_AGENT);
        is_last = ((old & (NN - 1u)) == NN - 1u);
    }
    __syncthreads();

    // ---- last block: fixed-order double reduction (deterministic)
    if (is_last) {
        double rs = (double)__hip_atomic_load(ws + WS_PART + 0*NN + t, __ATOMIC_RELAXED, __HIP_MEMORY_SCOPE_AGENT);
        double rc = (double)__hip_atomic_load(ws + WS_PART + 1*NN + t, __ATOMIC_RELAXED, __HIP_MEMORY_SCOPE_AGENT);
        double os = (double)__hip_atomic_load(ws + WS_PART + 2*NN + t, __ATOMIC_RELAXED, __HIP_MEMORY_SCOPE_AGENT);
        double oc = (double)__hip_atomic_load(ws + WS_PART + 3*NN + t, __ATOMIC_RELAXED, __HIP_MEMORY_SCOPE_AGENT);
        #pragma unroll
        for (int o = 32; o > 0; o >>= 1) {
            rs += __shfl_down(rs, o);
            rc += __shfl_down(rc, o);
            os += __shfl_down(os, o);
            oc += __shfl_down(oc, o);
        }
        if ((t & 63) == 0) {
            dred[wid*4+0] = rs; dred[wid*4+1] = rc;
            dred[wid*4+2] = os; dred[wid*4+3] = oc;
        }
        __syncthreads();
        if (t == 0) {
            double RS = 0, RC = 0, OS = 0, OC = 0;
            #pragma unroll
            for (int w = 0; w < 8; ++w) {
                RS += dred[w*4+0]; RC += dred[w*4+1];
                OS += dred[w*4+2]; OC += dred[w*4+3];
            }
            double ral = (RC > 0.0) ? RS / RC : 0.0;
            double oal = (OC > 0.0) ? -(OS / OC) : 0.0;
            out[0] = (float)(ral + oal);
        }
    }
}

extern "C" void kernel_launch(void* const* d_in, const int* in_sizes, int n_in,
                              void* d_out, int out_size, void* d_ws, size_t ws_size,
                              hipStream_t stream) {
    const float* features = (const float*)d_in[0];
    const float* labels   = (const float*)d_in[1];
    const float* v_prog   = (const float*)d_in[2];
    float* ws  = (float*)d_ws;
    float* out = (float*)d_out;

    hipLaunchKernelGGL(prep_kernel, dim3(1029), dim3(256), 0, stream,
                       features, labels, v_prog, ws);
    hipLaunchKernelGGL(main_kernel, dim3(NN),   dim3(512), 0, stream, labels, ws, out);
}

// Round 13
// 31.290 us; speedup vs baseline: 1.9611x; 1.0932x over previous
//
#include <hip/hip_runtime.h>
#include <math.h>

#define NN 512
#define DD 128
#define TEMP_INV (1.0f / 0.07f)
#define EPSF 1e-8f

// ws float-indexed layout (~1.08 MB used):
//   uint idx 32*s (s=0..7) : shard tickets (never reset; modulo-64; 128B apart)
//   uint idx 256  : global ticket (never reset; modulo-8)
//   288           : vn = ||v_prog|| + eps
//   512  +512     : sv[NN]    sorted positions (ascending)
//   1024 +512     : rk[NN]    (int) stable rank of element k
//   1536 +512     : proj[NN]  raw cf . v_prog
//   2048 +512     : sqn[NN]   ||cf_k||^2 (from Gram diagonal)
//   2560 +2048    : partials SoA float[4][NN] (agent-scope atomic stores)
//   8192 +262144  : G[NN][NN] raw Gram matrix cf @ cf^T
#define WS_TKG  256
#define WS_VN   288
#define WS_SV   512
#define WS_RK   1024
#define WS_PROJ 1536
#define WS_SQN  2048
#define WS_PART 2560
#define WS_G    8192

// prep grid: 0..1023 = gram 16x16 tiles | 1024,1025 = proj | 1026 = vn | 1027,1028 = ranks
__global__ __launch_bounds__(256) void prep_kernel(
    const float* __restrict__ features,
    const float* __restrict__ labels,
    const float* __restrict__ v_prog,
    float* __restrict__ ws)
{
    const int b = blockIdx.x;
    const int t = threadIdx.x;
    if (b < 1024) {
        // ---- Gram tile (tr,tc): G[16tr..+16][16tc..+16]; 132-float padded rows
        __shared__ __align__(16) float a_s[16 * 132];
        __shared__ __align__(16) float b_s[16 * 132];
        const int tr = b >> 5, tc = b & 31;
        {
            const int rl = t >> 5, q = t & 31;          // 8 rows per half
            const int ra0 = 16 * tr + rl, rb0 = 16 * tc + rl;
            const int ra1 = ra0 + 8,      rb1 = rb0 + 8;
            float4 va0 = ((const float4*)features)[((ra0 & 255) * 2 + (ra0 >> 8)) * 32 + q];
            float4 vb0 = ((const float4*)features)[((rb0 & 255) * 2 + (rb0 >> 8)) * 32 + q];
            float4 va1 = ((const float4*)features)[((ra1 & 255) * 2 + (ra1 >> 8)) * 32 + q];
            float4 vb1 = ((const float4*)features)[((rb1 & 255) * 2 + (rb1 >> 8)) * 32 + q];
            *(float4*)(a_s + (rl + 0) * 132 + 4 * q) = va0;
            *(float4*)(b_s + (rl + 0) * 132 + 4 * q) = vb0;
            *(float4*)(a_s + (rl + 8) * 132 + 4 * q) = va1;
            *(float4*)(b_s + (rl + 8) * 132 + 4 * q) = vb1;
        }
        __syncthreads();
        const int y = t >> 4, x = t & 15;
        const float4* arow = (const float4*)(a_s + y * 132);
        const float4* brow = (const float4*)(b_s + x * 132);
        float c0 = 0.f, c1 = 0.f, c2 = 0.f, c3 = 0.f;
        #pragma unroll 8
        for (int q = 0; q < 32; ++q) {
            float4 a = arow[q]; float4 v = brow[q];
            c0 += a.x * v.x; c1 += a.y * v.y; c2 += a.z * v.z; c3 += a.w * v.w;
        }
        const float c = (c0 + c1) + (c2 + c3);
        const int gr = 16 * tr + y, gc = 16 * tc + x;
        ws[WS_G + gr * NN + gc] = c;
        if (gr == gc) ws[WS_SQN + gr] = c;              // diagonal -> sqn[]
    } else if (b < 1026) {
        // ---- proj: row = (b-1024)*256 + t
        __shared__ __align__(16) float vp_s[DD];
        if (t < DD) vp_s[t] = v_prog[t];
        __syncthreads();
        const int row = (b - 1024) * 256 + t;
        const float4* src = (const float4*)features + ((row & 255) * 2 + (row >> 8)) * 32;
        const float4* v4 = (const float4*)vp_s;
        float p0 = 0.f, p1 = 0.f, p2 = 0.f, p3 = 0.f;
        #pragma unroll 8
        for (int q = 0; q < 32; ++q) {
            float4 a = src[q]; float4 v = v4[q];
            p0 += a.x*v.x; p1 += a.y*v.y; p2 += a.z*v.z; p3 += a.w*v.w;
        }
        ws[WS_PROJ + row] = (p0 + p1) + (p2 + p3);
    } else if (b == 1026) {
        // ---- vn
        __shared__ float s0[4];
        float x = (t < DD) ? v_prog[t] : 0.f;
        float s = x * x;
        #pragma unroll
        for (int o = 32; o > 0; o >>= 1) s += __shfl_down(s, o);
        if ((t & 63) == 0) s0[t >> 6] = s;
        __syncthreads();
        if (t == 0) ws[WS_VN] = sqrtf(s0[0] + s0[1] + s0[2] + s0[3]) + EPSF;
    } else {
        // ---- ranks: k = (b-1027)*256 + t
        __shared__ __align__(16) float pos_s[NN];
        const int k = (b - 1027) * 256 + t;
        for (int m = t; m < NN; m += 256) pos_s[m] = labels[m & 255];
        __syncthreads();
        const float pk = pos_s[k];
        const float4* p4 = (const float4*)pos_s;
        int r = 0;
        #pragma unroll 8
        for (int q = 0; q < NN / 4; ++q) {
            float4 v = p4[q];
            const int m0 = 4 * q;
            r += (int)(v.x < pk) | ((int)(v.x == pk) & (int)(m0 + 0 < k));
            r += (int)(v.y < pk) | ((int)(v.y == pk) & (int)(m0 + 1 < k));
            r += (int)(v.z < pk) | ((int)(v.z == pk) & (int)(m0 + 2 < k));
            r += (int)(v.w < pk) | ((int)(v.w == pk) & (int)(m0 + 3 < k));
        }
        ws[WS_SV + r] = pk;                 // unique slot (stable tie-break)
        ((int*)ws)[WS_RK + k] = r;
    }
}

// One block (512 threads) per row i; thread t is both k=t and j=t.
// Finale folded in: sc1 partial stores + vmcnt drain + SHARDED relaxed tickets
// (8 lines x 64 blocks -> parallel RMW chains), shard-lasts bump a global ticket.
__global__ __launch_bounds__(512) void main_kernel(
    const float* __restrict__ labels,
    float* __restrict__ ws,
    float* __restrict__ out)
{
    __shared__ float sv_s[NN];
    __shared__ float esS[NN];
    __shared__ float wtot[8];
    __shared__ float red_s[32];
    __shared__ double dred[32];
    __shared__ int is_last;

    const int i = blockIdx.x;
    const int t = threadIdx.x;
    const int wid = t >> 6;

    sv_s[t] = ws[WS_SV + t];
    const int rk_t = ((const int*)ws)[WS_RK + t];
    const int rk_i = ((const int*)ws)[WS_RK + i];      // uniform
    const float g      = ws[WS_G + i * NN + t];        // coalesced Gram row
    const float sqn_i  = ws[WS_SQN + i];               // uniform
    const float sqn_k  = ws[WS_SQN + t];               // coalesced
    const float proj_i = ws[WS_PROJ + i];
    const float proj_k = ws[WS_PROJ + t];
    const float vn     = ws[WS_VN];
    const float pos_i  = labels[i & 255];
    const float pos_k  = labels[t & 255];

    const float inv_ni = 1.0f / fmaxf(sqrtf(sqn_i), 1e-12f);
    const float inv_nk = 1.0f / fmaxf(sqrtf(sqn_k), 1e-12f);
    const float sim    = g * inv_ni * inv_nk * TEMP_INV;
    const float es     = (t == i) ? 0.0f : __expf(sim);   // k==i excluded
    esS[rk_t] = es;                                        // scatter to sorted slot

    float oal_sum = 0.f, oal_cnt = 0.f;
    if (pos_i < pos_k) {
        float sqd  = fmaxf(sqn_i + sqn_k - 2.0f * g, 0.0f);
        float dist = sqrtf(fmaxf(sqd, 1e-24f));
        oal_sum = (proj_k - proj_i) / (vn * fmaxf(dist, 1e-12f));
        oal_cnt = 1.0f;
    }
    __syncthreads();   // sv_s + esS complete

    // ---- inclusive prefix scan of esS[512]
    float s = esS[t];
    #pragma unroll
    for (int off = 1; off < 64; off <<= 1) {
        float u = __shfl_up(s, off);
        if ((t & 63) >= off) s += u;
    }
    if ((t & 63) == 63) wtot[wid] = s;
    __syncthreads();
    float woff = 0.f;
    for (int w = 0; w < wid; ++w) woff += wtot[w];    // wave-uniform
    esS[t] = s + woff;
    __syncthreads();
    const float total = esS[NN - 1];

    // ---- denom: interval of {k : |p_i - p_k| < thr}; split at rk_i; lo/hi interleaved
    const float thr = fabsf(pos_i - pos_k);           // pd[i][j], j==t
    int lo = 0, hi = rk_i;
    #pragma unroll
    for (int step = 256; step > 0; step >>= 1) {
        if (lo + step <= rk_i && !(fabsf(pos_i - sv_s[lo + step - 1]) < thr)) lo += step;
        if (hi + step <= NN   &&  (fabsf(pos_i - sv_s[hi + step - 1]) < thr)) hi += step;
    }

    const float pe_lo = (lo > 0) ? esS[lo - 1] : 0.0f;
    const float pe_hi = (hi > 0) ? esS[hi - 1] : 0.0f;
    float ral_sum = 0.f, ral_cnt = 0.f;
    if (t != i) {
        float denom = fmaxf(pe_lo + (total - pe_hi), es);   // k=j always in set
        const float sw = 1.0f / (1.0f + __expf(-thr));      // sigmoid(pd)
        ral_sum = (__logf(denom + EPSF) - sim) * sw;        // -log(es/(denom+eps))
        ral_cnt = 1.0f;
    }

    // ---- block reduce
    #pragma unroll
    for (int o = 32; o > 0; o >>= 1) {
        ral_sum += __shfl_down(ral_sum, o);
        ral_cnt += __shfl_down(ral_cnt, o);
        oal_sum += __shfl_down(oal_sum, o);
        oal_cnt += __shfl_down(oal_cnt, o);
    }
    if ((t & 63) == 0) {
        red_s[wid*4+0] = ral_sum; red_s[wid*4+1] = ral_cnt;
        red_s[wid*4+2] = oal_sum; red_s[wid*4+3] = oal_cnt;
    }
    __syncthreads();
    if (t == 0) {
        float rs = 0.f, rc = 0.f, os = 0.f, oc = 0.f;
        #pragma unroll
        for (int w = 0; w < 8; ++w) {
            rs += red_s[w*4+0]; rc += red_s[w*4+1];
            os += red_s[w*4+2]; oc += red_s[w*4+3];
        }
        // agent-scope relaxed atomic stores: write through to coherent point (sc1)
        __hip_atomic_store(ws + WS_PART + 0*NN + i, rs, __ATOMIC_RELAXED, __HIP_MEMORY_SCOPE_AGENT);
        __hip_atomic_store(ws + WS_PART + 1*NN + i, rc, __ATOMIC_RELAXED, __HIP_MEMORY_SCOPE_AGENT);
        __hip_atomic_store(ws + WS_PART + 2*NN + i, os, __ATOMIC_RELAXED, __HIP_MEMORY_SCOPE_AGENT);
        __hip_atomic_store(ws + WS_PART + 3*NN + i, oc, __ATOMIC_RELAXED, __HIP_MEMORY_SCOPE_AGENT);
        // drain stores to the coherent point, then SHARDED relaxed ticket
        asm volatile("s_waitcnt vmcnt(0)" ::: "memory");
        const int sh = i >> 6;                        // 8 shards x 64 blocks
        unsigned old = __hip_atomic_fetch_add((unsigned*)ws + 32 * sh, 1u,
                                              __ATOMIC_RELAXED, __HIP_MEMORY_SCOPE_AGENT);
        int lastg = 0;
        if ((old & 63u) == 63u) {                     // shard complete (2^32 % 64 == 0)
            unsigned gold = __hip_atomic_fetch_add((unsigned*)ws + WS_TKG, 1u,
                                                   __ATOMIC_RELAXED, __HIP_MEMORY_SCOPE_AGENT);
            lastg = ((gold & 7u) == 7u);              // all 8 shards (2^32 % 8 == 0)
        }
        is_last = lastg;
    }
    __syncthreads();

    // ---- last block: fixed-order double reduction (deterministic)
    if (is_last) {
        double rs = (double)__hip_atomic_load(ws + WS_PART + 0*NN + t, __ATOMIC_RELAXED, __HIP_MEMORY_SCOPE_AGENT);
        double rc = (double)__hip_atomic_load(ws + WS_PART + 1*NN + t, __ATOMIC_RELAXED, __HIP_MEMORY_SCOPE_AGENT);
        double os = (double)__hip_atomic_load(ws + WS_PART + 2*NN + t, __ATOMIC_RELAXED, __HIP_MEMORY_SCOPE_AGENT);
        double oc = (double)__hip_atomic_load(ws + WS_PART + 3*NN + t, __ATOMIC_RELAXED, __HIP_MEMORY_SCOPE_AGENT);
        #pragma unroll
        for (int o = 32; o > 0; o >>= 1) {
            rs += __shfl_down(rs, o);
            rc += __shfl_down(rc, o);
            os += __shfl_down(os, o);
            oc += __shfl_down(oc, o);
        }
        if ((t & 63) == 0) {
            dred[wid*4+0] = rs; dred[wid*4+1] = rc;
            dred[wid*4+2] = os; dred[wid*4+3] = oc;
        }
        __syncthreads();
        if (t == 0) {
            double RS = 0, RC = 0, OS = 0, OC = 0;
            #pragma unroll
            for (int w = 0; w < 8; ++w) {
                RS += dred[w*4+0]; RC += dred[w*4+1];
                OS += dred[w*4+2]; OC += dred[w*4+3];
            }
            double ral = (RC > 0.0) ? RS / RC : 0.0;
            double oal = (OC > 0.0) ? -(OS / OC) : 0.0;
            out[0] = (float)(ral + oal);
        }
    }
}

extern "C" void kernel_launch(void* const* d_in, const int* in_sizes, int n_in,
                              void* d_out, int out_size, void* d_ws, size_t ws_size,
                              hipStream_t stream) {
    const float* features = (const float*)d_in[0];
    const float* labels   = (const float*)d_in[1];
    const float* v_prog   = (const float*)d_in[2];
    float* ws  = (float*)d_ws;
    float* out = (float*)d_out;

    hipLaunchKernelGGL(prep_kernel, dim3(1029), dim3(256), 0, stream,
                       features, labels, v_prog, ws);
    hipLaunchKernelGGL(main_kernel, dim3(NN),   dim3(512), 0, stream, labels, ws, out);
}

// Round 14
// 30.942 us; speedup vs baseline: 1.9831x; 1.0112x over previous
//
#include <hip/hip_runtime.h>
#include <math.h>

#define NN 512
#define DD 128
#define TEMP_INV (1.0f / 0.07f)
#define EPSF 1e-8f

// ws float-indexed layout (~1.08 MB used):
//   uint idx 32*s (s=0..7) : shard tickets (never reset; modulo-64; 128B apart)
//   uint idx 256  : global ticket (never reset; modulo-8)
//   288           : vn = ||v_prog|| + eps
//   512  +512     : sv[NN]    sorted positions (ascending)
//   1024 +512     : rk[NN]    (int) stable rank of element k
//   1536 +512     : proj[NN]  raw cf . v_prog
//   2048 +512     : sqn[NN]   ||cf_k||^2 (Gram diagonal)
//   2560 +512     : invn[NN]  1/max(sqrt(sqn),1e-12)
//   3072 +2048    : partials SoA float[4][NN] (agent-scope sc1 stores)
//   8192 +262144  : G[NN][NN] raw Gram matrix cf @ cf^T
#define WS_TKG  256
#define WS_VN   288
#define WS_SV   512
#define WS_RK   1024
#define WS_PROJ 1536
#define WS_SQN  2048
#define WS_INVN 2560
#define WS_PART 3072
#define WS_G    8192

// prep grid: 0..1023 = gram 16x16 tiles | 1024,1025 = proj | 1026 = vn | 1027,1028 = ranks
__global__ __launch_bounds__(256) void prep_kernel(
    const float* __restrict__ features,
    const float* __restrict__ labels,
    const float* __restrict__ v_prog,
    float* __restrict__ ws)
{
    const int b = blockIdx.x;
    const int t = threadIdx.x;
    if (b < 1024) {
        __shared__ __align__(16) float a_s[16 * 132];
        __shared__ __align__(16) float b_s[16 * 132];
        const int tr = b >> 5, tc = b & 31;
        {
            const int rl = t >> 5, q = t & 31;          // 8 rows per half
            const int ra0 = 16 * tr + rl, rb0 = 16 * tc + rl;
            const int ra1 = ra0 + 8,      rb1 = rb0 + 8;
            float4 va0 = ((const float4*)features)[((ra0 & 255) * 2 + (ra0 >> 8)) * 32 + q];
            float4 vb0 = ((const float4*)features)[((rb0 & 255) * 2 + (rb0 >> 8)) * 32 + q];
            float4 va1 = ((const float4*)features)[((ra1 & 255) * 2 + (ra1 >> 8)) * 32 + q];
            float4 vb1 = ((const float4*)features)[((rb1 & 255) * 2 + (rb1 >> 8)) * 32 + q];
            *(float4*)(a_s + (rl + 0) * 132 + 4 * q) = va0;
            *(float4*)(b_s + (rl + 0) * 132 + 4 * q) = vb0;
            *(float4*)(a_s + (rl + 8) * 132 + 4 * q) = va1;
            *(float4*)(b_s + (rl + 8) * 132 + 4 * q) = vb1;
        }
        __syncthreads();
        const int y = t >> 4, x = t & 15;
        const float4* arow = (const float4*)(a_s + y * 132);
        const float4* brow = (const float4*)(b_s + x * 132);
        float c0 = 0.f, c1 = 0.f, c2 = 0.f, c3 = 0.f;
        #pragma unroll 8
        for (int q = 0; q < 32; ++q) {
            float4 a = arow[q]; float4 v = brow[q];
            c0 += a.x * v.x; c1 += a.y * v.y; c2 += a.z * v.z; c3 += a.w * v.w;
        }
        const float c = (c0 + c1) + (c2 + c3);
        const int gr = 16 * tr + y, gc = 16 * tc + x;
        ws[WS_G + gr * NN + gc] = c;
        if (gr == gc) {
            ws[WS_SQN  + gr] = c;                       // diagonal -> sqn[]
            ws[WS_INVN + gr] = 1.0f / fmaxf(sqrtf(c), 1e-12f);
        }
    } else if (b < 1026) {
        // ---- proj: row = (b-1024)*256 + t
        __shared__ __align__(16) float vp_s[DD];
        if (t < DD) vp_s[t] = v_prog[t];
        __syncthreads();
        const int row = (b - 1024) * 256 + t;
        const float4* src = (const float4*)features + ((row & 255) * 2 + (row >> 8)) * 32;
        const float4* v4 = (const float4*)vp_s;
        float p0 = 0.f, p1 = 0.f, p2 = 0.f, p3 = 0.f;
        #pragma unroll 8
        for (int q = 0; q < 32; ++q) {
            float4 a = src[q]; float4 v = v4[q];
            p0 += a.x*v.x; p1 += a.y*v.y; p2 += a.z*v.z; p3 += a.w*v.w;
        }
        ws[WS_PROJ + row] = (p0 + p1) + (p2 + p3);
    } else if (b == 1026) {
        // ---- vn
        __shared__ float s0[4];
        float x = (t < DD) ? v_prog[t] : 0.f;
        float s = x * x;
        #pragma unroll
        for (int o = 32; o > 0; o >>= 1) s += __shfl_down(s, o);
        if ((t & 63) == 0) s0[t >> 6] = s;
        __syncthreads();
        if (t == 0) ws[WS_VN] = sqrtf(s0[0] + s0[1] + s0[2] + s0[3]) + EPSF;
    } else {
        // ---- ranks: k = (b-1027)*256 + t
        __shared__ __align__(16) float pos_s[NN];
        const int k = (b - 1027) * 256 + t;
        for (int m = t; m < NN; m += 256) pos_s[m] = labels[m & 255];
        __syncthreads();
        const float pk = pos_s[k];
        const float4* p4 = (const float4*)pos_s;
        int r = 0;
        #pragma unroll 8
        for (int q = 0; q < NN / 4; ++q) {
            float4 v = p4[q];
            const int m0 = 4 * q;
            r += (int)(v.x < pk) | ((int)(v.x == pk) & (int)(m0 + 0 < k));
            r += (int)(v.y < pk) | ((int)(v.y == pk) & (int)(m0 + 1 < k));
            r += (int)(v.z < pk) | ((int)(v.z == pk) & (int)(m0 + 2 < k));
            r += (int)(v.w < pk) | ((int)(v.w == pk) & (int)(m0 + 3 < k));
        }
        ws[WS_SV + r] = pk;                 // unique slot (stable tie-break)
        ((int*)ws)[WS_RK + k] = r;
    }
}

// One block (256 threads) per row i; thread t handles elements e0=2t, e1=2t+1
// for BOTH k and j roles -> 2x ILP on every latency chain.
__global__ __launch_bounds__(256) void main_kernel(
    const float* __restrict__ labels,
    float* __restrict__ ws,
    float* __restrict__ out)
{
    __shared__ float sv_s[NN];
    __shared__ float esS[NN];
    __shared__ float wtot[4];
    __shared__ float red_s[16];
    __shared__ double dred[16];
    __shared__ int is_last;

    const int i = blockIdx.x;
    const int t = threadIdx.x;
    const int wid = t >> 6;
    const int e0 = 2 * t;

    // paired (float2/int2) coalesced loads
    *(float2*)&sv_s[e0] = *(const float2*)(ws + WS_SV + e0);
    const int2   rk2  = *(const int2*)((const int*)ws + WS_RK + e0);
    const float2 g2   = *(const float2*)(ws + WS_G + i * NN + e0);
    const float2 sqn2 = *(const float2*)(ws + WS_SQN + e0);
    const float2 pj2  = *(const float2*)(ws + WS_PROJ + e0);
    const float2 in2  = *(const float2*)(ws + WS_INVN + e0);
    const float2 lab  = *(const float2*)(labels + (e0 & 255));
    const int   rk_i   = ((const int*)ws)[WS_RK + i];     // uniform
    const float sqn_i  = ws[WS_SQN + i];
    const float proj_i = ws[WS_PROJ + i];
    const float invn_i = ws[WS_INVN + i];
    const float vn     = ws[WS_VN];
    const float pos_i  = labels[i & 255];

    const float sim0 = g2.x * invn_i * in2.x * TEMP_INV;
    const float sim1 = g2.y * invn_i * in2.y * TEMP_INV;
    const float es0  = (e0     == i) ? 0.0f : __expf(sim0);
    const float es1  = (e0 + 1 == i) ? 0.0f : __expf(sim1);
    esS[rk2.x] = es0;                                     // scatter to sorted slots
    esS[rk2.y] = es1;

    float oal_sum = 0.f, oal_cnt = 0.f;
    if (pos_i < lab.x) {
        float sqd  = fmaxf(sqn_i + sqn2.x - 2.0f * g2.x, 0.0f);
        float dist = sqrtf(fmaxf(sqd, 1e-24f));
        oal_sum += (pj2.x - proj_i) / (vn * fmaxf(dist, 1e-12f));
        oal_cnt += 1.0f;
    }
    if (pos_i < lab.y) {
        float sqd  = fmaxf(sqn_i + sqn2.y - 2.0f * g2.y, 0.0f);
        float dist = sqrtf(fmaxf(sqd, 1e-24f));
        oal_sum += (pj2.y - proj_i) / (vn * fmaxf(dist, 1e-12f));
        oal_cnt += 1.0f;
    }
    __syncthreads();   // sv_s + esS complete

    // ---- inclusive prefix scan of esS[512] (pairwise, 256 threads)
    const float2 ee = *(const float2*)&esS[e0];
    float p = ee.x + ee.y;
    float s = p;
    #pragma unroll
    for (int off = 1; off < 64; off <<= 1) {
        float u = __shfl_up(s, off);
        if ((t & 63) >= off) s += u;
    }
    if ((t & 63) == 63) wtot[wid] = s;
    __syncthreads();
    float woff = 0.f;
    for (int w = 0; w < wid; ++w) woff += wtot[w];    // wave-uniform
    const float inc = s + woff;                       // inclusive through pair
    esS[e0]     = inc - ee.y;                         // inclusive through e0
    esS[e0 + 1] = inc;
    __syncthreads();
    const float total = esS[NN - 1];

    // ---- denoms: 4 independent binary-search chains interleaved
    const float thr0 = fabsf(pos_i - lab.x);
    const float thr1 = fabsf(pos_i - lab.y);
    int lo0 = 0, hi0 = rk_i, lo1 = 0, hi1 = rk_i;
    #pragma unroll
    for (int step = 256; step > 0; step >>= 1) {
        if (lo0 + step <= rk_i && !(fabsf(pos_i - sv_s[lo0 + step - 1]) < thr0)) lo0 += step;
        if (hi0 + step <= NN   &&  (fabsf(pos_i - sv_s[hi0 + step - 1]) < thr0)) hi0 += step;
        if (lo1 + step <= rk_i && !(fabsf(pos_i - sv_s[lo1 + step - 1]) < thr1)) lo1 += step;
        if (hi1 + step <= NN   &&  (fabsf(pos_i - sv_s[hi1 + step - 1]) < thr1)) hi1 += step;
    }

    float ral_sum = 0.f, ral_cnt = 0.f;
    {
        const float pe_lo = (lo0 > 0) ? esS[lo0 - 1] : 0.0f;
        const float pe_hi = (hi0 > 0) ? esS[hi0 - 1] : 0.0f;
        if (e0 != i) {
            float denom = fmaxf(pe_lo + (total - pe_hi), es0);  // k=j always in set
            const float sw = 1.0f / (1.0f + __expf(-thr0));
            ral_sum += (__logf(denom + EPSF) - sim0) * sw;
            ral_cnt += 1.0f;
        }
    }
    {
        const float pe_lo = (lo1 > 0) ? esS[lo1 - 1] : 0.0f;
        const float pe_hi = (hi1 > 0) ? esS[hi1 - 1] : 0.0f;
        if (e0 + 1 != i) {
            float denom = fmaxf(pe_lo + (total - pe_hi), es1);
            const float sw = 1.0f / (1.0f + __expf(-thr1));
            ral_sum += (__logf(denom + EPSF) - sim1) * sw;
            ral_cnt += 1.0f;
        }
    }

    // ---- block reduce (4 waves)
    #pragma unroll
    for (int o = 32; o > 0; o >>= 1) {
        ral_sum += __shfl_down(ral_sum, o);
        ral_cnt += __shfl_down(ral_cnt, o);
        oal_sum += __shfl_down(oal_sum, o);
        oal_cnt += __shfl_down(oal_cnt, o);
    }
    if ((t & 63) == 0) {
        red_s[wid*4+0] = ral_sum; red_s[wid*4+1] = ral_cnt;
        red_s[wid*4+2] = oal_sum; red_s[wid*4+3] = oal_cnt;
    }
    __syncthreads();
    if (t == 0) {
        float rs = 0.f, rc = 0.f, os = 0.f, oc = 0.f;
        #pragma unroll
        for (int w = 0; w < 4; ++w) {
            rs += red_s[w*4+0]; rc += red_s[w*4+1];
            os += red_s[w*4+2]; oc += red_s[w*4+3];
        }
        // sc1 write-through partials + vmcnt drain + sharded relaxed tickets (R13-validated)
        __hip_atomic_store(ws + WS_PART + 0*NN + i, rs, __ATOMIC_RELAXED, __HIP_MEMORY_SCOPE_AGENT);
        __hip_atomic_store(ws + WS_PART + 1*NN + i, rc, __ATOMIC_RELAXED, __HIP_MEMORY_SCOPE_AGENT);
        __hip_atomic_store(ws + WS_PART + 2*NN + i, os, __ATOMIC_RELAXED, __HIP_MEMORY_SCOPE_AGENT);
        __hip_atomic_store(ws + WS_PART + 3*NN + i, oc, __ATOMIC_RELAXED, __HIP_MEMORY_SCOPE_AGENT);
        asm volatile("s_waitcnt vmcnt(0)" ::: "memory");
        const int sh = i >> 6;                        // 8 shards x 64 blocks
        unsigned old = __hip_atomic_fetch_add((unsigned*)ws + 32 * sh, 1u,
                                              __ATOMIC_RELAXED, __HIP_MEMORY_SCOPE_AGENT);
        int lastg = 0;
        if ((old & 63u) == 63u) {                     // shard complete (2^32 % 64 == 0)
            unsigned gold = __hip_atomic_fetch_add((unsigned*)ws + WS_TKG, 1u,
                                                   __ATOMIC_RELAXED, __HIP_MEMORY_SCOPE_AGENT);
            lastg = ((gold & 7u) == 7u);              // all 8 shards
        }
        is_last = lastg;
    }
    __syncthreads();

    // ---- last block: fixed-order double reduction (deterministic)
    if (is_last) {
        double rs = (double)__hip_atomic_load(ws + WS_PART + 0*NN + e0, __ATOMIC_RELAXED, __HIP_MEMORY_SCOPE_AGENT)
                  + (double)__hip_atomic_load(ws + WS_PART + 0*NN + e0 + 1, __ATOMIC_RELAXED, __HIP_MEMORY_SCOPE_AGENT);
        double rc = (double)__hip_atomic_load(ws + WS_PART + 1*NN + e0, __ATOMIC_RELAXED, __HIP_MEMORY_SCOPE_AGENT)
                  + (double)__hip_atomic_load(ws + WS_PART + 1*NN + e0 + 1, __ATOMIC_RELAXED, __HIP_MEMORY_SCOPE_AGENT);
        double os = (double)__hip_atomic_load(ws + WS_PART + 2*NN + e0, __ATOMIC_RELAXED, __HIP_MEMORY_SCOPE_AGENT)
                  + (double)__hip_atomic_load(ws + WS_PART + 2*NN + e0 + 1, __ATOMIC_RELAXED, __HIP_MEMORY_SCOPE_AGENT);
        double oc = (double)__hip_atomic_load(ws + WS_PART + 3*NN + e0, __ATOMIC_RELAXED, __HIP_MEMORY_SCOPE_AGENT)
                  + (double)__hip_atomic_load(ws + WS_PART + 3*NN + e0 + 1, __ATOMIC_RELAXED, __HIP_MEMORY_SCOPE_AGENT);
        #pragma unroll
        for (int o = 32; o > 0; o >>= 1) {
            rs += __shfl_down(rs, o);
            rc += __shfl_down(rc, o);
            os += __shfl_down(os, o);
            oc += __shfl_down(oc, o);
        }
        if ((t & 63) == 0) {
            dred[wid*4+0] = rs; dred[wid*4+1] = rc;
            dred[wid*4+2] = os; dred[wid*4+3] = oc;
        }
        __syncthreads();
        if (t == 0) {
            double RS = 0, RC = 0, OS = 0, OC = 0;
            #pragma unroll
            for (int w = 0; w < 4; ++w) {
                RS += dred[w*4+0]; RC += dred[w*4+1];
                OS += dred[w*4+2]; OC += dred[w*4+3];
            }
            double ral = (RC > 0.0) ? RS / RC : 0.0;
            double oal = (OC > 0.0) ? -(OS / OC) : 0.0;
            out[0] = (float)(ral + oal);
        }
    }
}

extern "C" void kernel_launch(void* const* d_in, const int* in_sizes, int n_in,
                              void* d_out, int out_size, void* d_ws, size_t ws_size,
                              hipStream_t stream) {
    const float* features = (const float*)d_in[0];
    const float* labels   = (const float*)d_in[1];
    const float* v_prog   = (const float*)d_in[2];
    float* ws  = (float*)d_ws;
    float* out = (float*)d_out;

    hipLaunchKernelGGL(prep_kernel, dim3(1029), dim3(256), 0, stream,
                       features, labels, v_prog, ws);
    hipLaunchKernelGGL(main_kernel, dim3(NN),   dim3(256), 0, stream, labels, ws, out);
}

// Round 15
// 29.864 us; speedup vs baseline: 2.0547x; 1.0361x over previous
//
#include <hip/hip_runtime.h>
#include <math.h>

#define NN 512
#define DD 128
#define TEMP_INV (1.0f / 0.07f)
#define EPSF 1e-8f

// ws float-indexed layout (~1.08 MB used):
//   uint idx 32*s (s=0..7) : shard tickets (never reset; modulo-64; 128B apart)
//   uint idx 256  : global ticket (never reset; modulo-8)
//   288           : vn = ||v_prog|| + eps
//   512  +512     : sv[NN]    sorted positions (ascending)
//   1024 +512     : rk[NN]    (int) stable rank of element k
//   1536 +512     : proj[NN]  raw cf . v_prog
//   2048 +512     : sqn[NN]   ||cf_k||^2 (Gram diagonal)
//   2560 +512     : invn[NN]  1/max(sqrt(sqn),1e-12)
//   3072 +2048    : partials SoA float[4][NN] (agent-scope sc1 stores)
//   8192 +262144  : G[NN][NN] raw Gram matrix cf @ cf^T
#define WS_TKG  256
#define WS_VN   288
#define WS_SV   512
#define WS_RK   1024
#define WS_PROJ 1536
#define WS_SQN  2048
#define WS_INVN 2560
#define WS_PART 3072
#define WS_G    8192

#define NTILE 32                 // 16x16 tiles per side
#define NTRI  (NTILE*(NTILE+1)/2)   // 528 upper-triangle tiles

// prep grid: 0..527 = upper-tri gram tiles | 528,529 = proj | 530 = vn | 531,532 = ranks
__global__ __launch_bounds__(256) void prep_kernel(
    const float* __restrict__ features,
    const float* __restrict__ labels,
    const float* __restrict__ v_prog,
    float* __restrict__ ws)
{
    const int b = blockIdx.x;
    const int t = threadIdx.x;
    if (b < NTRI) {
        // ---- decode upper-triangle index b -> (tr, tc), tr <= tc
        int tr = (int)floorf(32.5f - sqrtf(32.5f * 32.5f - 2.0f * (float)b));
        // safety adjust for float rounding
        while (tr > 0 && b < tr * (65 - tr) / 2) --tr;
        while (b >= (tr + 1) * (64 - tr) / 2) ++tr;
        const int tc = tr + (b - tr * (65 - tr) / 2);

        __shared__ __align__(16) float a_s[16 * 132];
        __shared__ __align__(16) float b_s[16 * 132];
        {
            const int rl = t >> 5, q = t & 31;          // 8 rows per half
            const int ra0 = 16 * tr + rl, rb0 = 16 * tc + rl;
            const int ra1 = ra0 + 8,      rb1 = rb0 + 8;
            float4 va0 = ((const float4*)features)[((ra0 & 255) * 2 + (ra0 >> 8)) * 32 + q];
            float4 vb0 = ((const float4*)features)[((rb0 & 255) * 2 + (rb0 >> 8)) * 32 + q];
            float4 va1 = ((const float4*)features)[((ra1 & 255) * 2 + (ra1 >> 8)) * 32 + q];
            float4 vb1 = ((const float4*)features)[((rb1 & 255) * 2 + (rb1 >> 8)) * 32 + q];
            *(float4*)(a_s + (rl + 0) * 132 + 4 * q) = va0;
            *(float4*)(b_s + (rl + 0) * 132 + 4 * q) = vb0;
            *(float4*)(a_s + (rl + 8) * 132 + 4 * q) = va1;
            *(float4*)(b_s + (rl + 8) * 132 + 4 * q) = vb1;
        }
        __syncthreads();
        const int y = t >> 4, x = t & 15;
        const float4* arow = (const float4*)(a_s + y * 132);
        const float4* brow = (const float4*)(b_s + x * 132);
        float c0 = 0.f, c1 = 0.f, c2 = 0.f, c3 = 0.f;
        #pragma unroll 8
        for (int q = 0; q < 32; ++q) {
            float4 a = arow[q]; float4 v = brow[q];
            c0 += a.x * v.x; c1 += a.y * v.y; c2 += a.z * v.z; c3 += a.w * v.w;
        }
        const float c = (c0 + c1) + (c2 + c3);
        const int gr = 16 * tr + y, gc = 16 * tc + x;
        ws[WS_G + gr * NN + gc] = c;                    // upper
        if (tr != tc) {
            ws[WS_G + gc * NN + gr] = c;                // mirror (bitwise same value)
        } else if (gr == gc) {
            ws[WS_SQN  + gr] = c;                       // diagonal -> sqn[]
            ws[WS_INVN + gr] = 1.0f / fmaxf(sqrtf(c), 1e-12f);
        }
    } else if (b < NTRI + 2) {
        // ---- proj: row = (b-NTRI)*256 + t
        __shared__ __align__(16) float vp_s[DD];
        if (t < DD) vp_s[t] = v_prog[t];
        __syncthreads();
        const int row = (b - NTRI) * 256 + t;
        const float4* src = (const float4*)features + ((row & 255) * 2 + (row >> 8)) * 32;
        const float4* v4 = (const float4*)vp_s;
        float p0 = 0.f, p1 = 0.f, p2 = 0.f, p3 = 0.f;
        #pragma unroll 8
        for (int q = 0; q < 32; ++q) {
            float4 a = src[q]; float4 v = v4[q];
            p0 += a.x*v.x; p1 += a.y*v.y; p2 += a.z*v.z; p3 += a.w*v.w;
        }
        ws[WS_PROJ + row] = (p0 + p1) + (p2 + p3);
    } else if (b == NTRI + 2) {
        // ---- vn
        __shared__ float s0[4];
        float x = (t < DD) ? v_prog[t] : 0.f;
        float s = x * x;
        #pragma unroll
        for (int o = 32; o > 0; o >>= 1) s += __shfl_down(s, o);
        if ((t & 63) == 0) s0[t >> 6] = s;
        __syncthreads();
        if (t == 0) ws[WS_VN] = sqrtf(s0[0] + s0[1] + s0[2] + s0[3]) + EPSF;
    } else {
        // ---- ranks: k = (b-(NTRI+3))*256 + t
        __shared__ __align__(16) float pos_s[NN];
        const int k = (b - (NTRI + 3)) * 256 + t;
        for (int m = t; m < NN; m += 256) pos_s[m] = labels[m & 255];
        __syncthreads();
        const float pk = pos_s[k];
        const float4* p4 = (const float4*)pos_s;
        int r = 0;
        #pragma unroll 8
        for (int q = 0; q < NN / 4; ++q) {
            float4 v = p4[q];
            const int m0 = 4 * q;
            r += (int)(v.x < pk) | ((int)(v.x == pk) & (int)(m0 + 0 < k));
            r += (int)(v.y < pk) | ((int)(v.y == pk) & (int)(m0 + 1 < k));
            r += (int)(v.z < pk) | ((int)(v.z == pk) & (int)(m0 + 2 < k));
            r += (int)(v.w < pk) | ((int)(v.w == pk) & (int)(m0 + 3 < k));
        }
        ws[WS_SV + r] = pk;                 // unique slot (stable tie-break)
        ((int*)ws)[WS_RK + k] = r;
    }
}

// One block (256 threads) per row i; thread t handles elements e0=2t, e1=2t+1
// for BOTH k and j roles -> 2x ILP on every latency chain.
__global__ __launch_bounds__(256) void main_kernel(
    const float* __restrict__ labels,
    float* __restrict__ ws,
    float* __restrict__ out)
{
    __shared__ float sv_s[NN];
    __shared__ float esS[NN];
    __shared__ float wtot[4];
    __shared__ float red_s[16];
    __shared__ double dred[16];
    __shared__ int is_last;

    const int i = blockIdx.x;
    const int t = threadIdx.x;
    const int wid = t >> 6;
    const int e0 = 2 * t;

    // paired (float2/int2) coalesced loads
    *(float2*)&sv_s[e0] = *(const float2*)(ws + WS_SV + e0);
    const int2   rk2  = *(const int2*)((const int*)ws + WS_RK + e0);
    const float2 g2   = *(const float2*)(ws + WS_G + i * NN + e0);
    const float2 sqn2 = *(const float2*)(ws + WS_SQN + e0);
    const float2 pj2  = *(const float2*)(ws + WS_PROJ + e0);
    const float2 in2  = *(const float2*)(ws + WS_INVN + e0);
    const float2 lab  = *(const float2*)(labels + (e0 & 255));
    const int   rk_i   = ((const int*)ws)[WS_RK + i];     // uniform
    const float sqn_i  = ws[WS_SQN + i];
    const float proj_i = ws[WS_PROJ + i];
    const float invn_i = ws[WS_INVN + i];
    const float vn     = ws[WS_VN];
    const float pos_i  = labels[i & 255];

    const float sim0 = g2.x * invn_i * in2.x * TEMP_INV;
    const float sim1 = g2.y * invn_i * in2.y * TEMP_INV;
    const float es0  = (e0     == i) ? 0.0f : __expf(sim0);
    const float es1  = (e0 + 1 == i) ? 0.0f : __expf(sim1);
    esS[rk2.x] = es0;                                     // scatter to sorted slots
    esS[rk2.y] = es1;

    float oal_sum = 0.f, oal_cnt = 0.f;
    if (pos_i < lab.x) {
        float sqd  = fmaxf(sqn_i + sqn2.x - 2.0f * g2.x, 0.0f);
        float dist = sqrtf(fmaxf(sqd, 1e-24f));
        oal_sum += (pj2.x - proj_i) / (vn * fmaxf(dist, 1e-12f));
        oal_cnt += 1.0f;
    }
    if (pos_i < lab.y) {
        float sqd  = fmaxf(sqn_i + sqn2.y - 2.0f * g2.y, 0.0f);
        float dist = sqrtf(fmaxf(sqd, 1e-24f));
        oal_sum += (pj2.y - proj_i) / (vn * fmaxf(dist, 1e-12f));
        oal_cnt += 1.0f;
    }
    __syncthreads();   // sv_s + esS complete

    // ---- inclusive prefix scan of esS[512] (pairwise, 256 threads)
    const float2 ee = *(const float2*)&esS[e0];
    float p = ee.x + ee.y;
    float s = p;
    #pragma unroll
    for (int off = 1; off < 64; off <<= 1) {
        float u = __shfl_up(s, off);
        if ((t & 63) >= off) s += u;
    }
    if ((t & 63) == 63) wtot[wid] = s;
    __syncthreads();
    float woff = 0.f;
    for (int w = 0; w < wid; ++w) woff += wtot[w];    // wave-uniform
    const float inc = s + woff;                       // inclusive through pair
    esS[e0]     = inc - ee.y;                         // inclusive through e0
    esS[e0 + 1] = inc;
    __syncthreads();
    const float total = esS[NN - 1];

    // ---- denoms: 4 independent binary-search chains interleaved
    const float thr0 = fabsf(pos_i - lab.x);
    const float thr1 = fabsf(pos_i - lab.y);
    int lo0 = 0, hi0 = rk_i, lo1 = 0, hi1 = rk_i;
    #pragma unroll
    for (int step = 256; step > 0; step >>= 1) {
        if (lo0 + step <= rk_i && !(fabsf(pos_i - sv_s[lo0 + step - 1]) < thr0)) lo0 += step;
        if (hi0 + step <= NN   &&  (fabsf(pos_i - sv_s[hi0 + step - 1]) < thr0)) hi0 += step;
        if (lo1 + step <= rk_i && !(fabsf(pos_i - sv_s[lo1 + step - 1]) < thr1)) lo1 += step;
        if (hi1 + step <= NN   &&  (fabsf(pos_i - sv_s[hi1 + step - 1]) < thr1)) hi1 += step;
    }

    float ral_sum = 0.f, ral_cnt = 0.f;
    {
        const float pe_lo = (lo0 > 0) ? esS[lo0 - 1] : 0.0f;
        const float pe_hi = (hi0 > 0) ? esS[hi0 - 1] : 0.0f;
        if (e0 != i) {
            float denom = fmaxf(pe_lo + (total - pe_hi), es0);  // k=j always in set
            const float sw = 1.0f / (1.0f + __expf(-thr0));
            ral_sum += (__logf(denom + EPSF) - sim0) * sw;
            ral_cnt += 1.0f;
        }
    }
    {
        const float pe_lo = (lo1 > 0) ? esS[lo1 - 1] : 0.0f;
        const float pe_hi = (hi1 > 0) ? esS[hi1 - 1] : 0.0f;
        if (e0 + 1 != i) {
            float denom = fmaxf(pe_lo + (total - pe_hi), es1);
            const float sw = 1.0f / (1.0f + __expf(-thr1));
            ral_sum += (__logf(denom + EPSF) - sim1) * sw;
            ral_cnt += 1.0f;
        }
    }

    // ---- block reduce (4 waves)
    #pragma unroll
    for (int o = 32; o > 0; o >>= 1) {
        ral_sum += __shfl_down(ral_sum, o);
        ral_cnt += __shfl_down(ral_cnt, o);
        oal_sum += __shfl_down(oal_sum, o);
        oal_cnt += __shfl_down(oal_cnt, o);
    }
    if ((t & 63) == 0) {
        red_s[wid*4+0] = ral_sum; red_s[wid*4+1] = ral_cnt;
        red_s[wid*4+2] = oal_sum; red_s[wid*4+3] = oal_cnt;
    }
    __syncthreads();
    if (t == 0) {
        float rs = 0.f, rc = 0.f, os = 0.f, oc = 0.f;
        #pragma unroll
        for (int w = 0; w < 4; ++w) {
            rs += red_s[w*4+0]; rc += red_s[w*4+1];
            os += red_s[w*4+2]; oc += red_s[w*4+3];
        }
        // sc1 write-through partials + vmcnt drain + sharded relaxed tickets (R13-validated)
        __hip_atomic_store(ws + WS_PART + 0*NN + i, rs, __ATOMIC_RELAXED, __HIP_MEMORY_SCOPE_AGENT);
        __hip_atomic_store(ws + WS_PART + 1*NN + i, rc, __ATOMIC_RELAXED, __HIP_MEMORY_SCOPE_AGENT);
        __hip_atomic_store(ws + WS_PART + 2*NN + i, os, __ATOMIC_RELAXED, __HIP_MEMORY_SCOPE_AGENT);
        __hip_atomic_store(ws + WS_PART + 3*NN + i, oc, __ATOMIC_RELAXED, __HIP_MEMORY_SCOPE_AGENT);
        asm volatile("s_waitcnt vmcnt(0)" ::: "memory");
        const int sh = i >> 6;                        // 8 shards x 64 blocks
        unsigned old = __hip_atomic_fetch_add((unsigned*)ws + 32 * sh, 1u,
                                              __ATOMIC_RELAXED, __HIP_MEMORY_SCOPE_AGENT);
        int lastg = 0;
        if ((old & 63u) == 63u) {                     // shard complete (2^32 % 64 == 0)
            unsigned gold = __hip_atomic_fetch_add((unsigned*)ws + WS_TKG, 1u,
                                                   __ATOMIC_RELAXED, __HIP_MEMORY_SCOPE_AGENT);
            lastg = ((gold & 7u) == 7u);              // all 8 shards
        }
        is_last = lastg;
    }
    __syncthreads();

    // ---- last block: fixed-order double reduction (deterministic)
    if (is_last) {
        double rs = (double)__hip_atomic_load(ws + WS_PART + 0*NN + e0, __ATOMIC_RELAXED, __HIP_MEMORY_SCOPE_AGENT)
                  + (double)__hip_atomic_load(ws + WS_PART + 0*NN + e0 + 1, __ATOMIC_RELAXED, __HIP_MEMORY_SCOPE_AGENT);
        double rc = (double)__hip_atomic_load(ws + WS_PART + 1*NN + e0, __ATOMIC_RELAXED, __HIP_MEMORY_SCOPE_AGENT)
                  + (double)__hip_atomic_load(ws + WS_PART + 1*NN + e0 + 1, __ATOMIC_RELAXED, __HIP_MEMORY_SCOPE_AGENT);
        double os = (double)__hip_atomic_load(ws + WS_PART + 2*NN + e0, __ATOMIC_RELAXED, __HIP_MEMORY_SCOPE_AGENT)
                  + (double)__hip_atomic_load(ws + WS_PART + 2*NN + e0 + 1, __ATOMIC_RELAXED, __HIP_MEMORY_SCOPE_AGENT);
        double oc = (double)__hip_atomic_load(ws + WS_PART + 3*NN + e0, __ATOMIC_RELAXED, __HIP_MEMORY_SCOPE_AGENT)
                  + (double)__hip_atomic_load(ws + WS_PART + 3*NN + e0 + 1, __ATOMIC_RELAXED, __HIP_MEMORY_SCOPE_AGENT);
        #pragma unroll
        for (int o = 32; o > 0; o >>= 1) {
            rs += __shfl_down(rs, o);
            rc += __shfl_down(rc, o);
            os += __shfl_down(os, o);
            oc += __shfl_down(oc, o);
        }
        if ((t & 63) == 0) {
            dred[wid*4+0] = rs; dred[wid*4+1] = rc;
            dred[wid*4+2] = os; dred[wid*4+3] = oc;
        }
        __syncthreads();
        if (t == 0) {
            double RS = 0, RC = 0, OS = 0, OC = 0;
            #pragma unroll
            for (int w = 0; w < 4; ++w) {
                RS += dred[w*4+0]; RC += dred[w*4+1];
                OS += dred[w*4+2]; OC += dred[w*4+3];
            }
            double ral = (RC > 0.0) ? RS / RC : 0.0;
            double oal = (OC > 0.0) ? -(OS / OC) : 0.0;
            out[0] = (float)(ral + oal);
        }
    }
}

extern "C" void kernel_launch(void* const* d_in, const int* in_sizes, int n_in,
                              void* d_out, int out_size, void* d_ws, size_t ws_size,
                              hipStream_t stream) {
    const float* features = (const float*)d_in[0];
    const float* labels   = (const float*)d_in[1];
    const float* v_prog   = (const float*)d_in[2];
    float* ws  = (float*)d_ws;
    float* out = (float*)d_out;

    hipLaunchKernelGGL(prep_kernel, dim3(NTRI + 5), dim3(256), 0, stream,
                       features, labels, v_prog, ws);
    hipLaunchKernelGGL(main_kernel, dim3(NN), dim3(256), 0, stream, labels, ws, out);
}